// Round 6
// baseline (204.550 us; speedup 1.0000x reference)
//
#include <hip/hip_runtime.h>
#include <cmath>

#define C_DIM   1024
#define H_DIM   16
#define HD      64
#define N_TOK   2048
#define M_TOK   4096
#define LOG2E   1.44269504088896340736f

typedef _Float16 f16;
typedef __attribute__((ext_vector_type(8))) _Float16 f16x8;
typedef __attribute__((ext_vector_type(4))) _Float16 f16x4;
typedef __attribute__((ext_vector_type(2))) __fp16   fp16x2_b;  // builtin ret type
typedef __attribute__((ext_vector_type(4))) float    f32x4;

// async global->LDS, 16B per lane; LDS dest = wave-uniform base + lane*16
__device__ __forceinline__ void gl_lds16(const void* g, void* l) {
  __builtin_amdgcn_global_load_lds((const __attribute__((address_space(1))) void*)g,
                                   (__attribute__((address_space(3))) void*)l, 16, 0, 0);
}

// ---------------------------------------------------------------------------
// fp32 -> fp16 convert: x (4.19M), qkv_w (3.15M), proj_w (1.05M), float4/thread
// ---------------------------------------------------------------------------
#define CVT_X4 1048576
#define CVT_W4 786432
#define CVT_P4 262144
__global__ __launch_bounds__(256) void cvt_all(const float* __restrict__ x,
                                               const float* __restrict__ w1,
                                               const float* __restrict__ w2,
                                               f16* __restrict__ xh,
                                               f16* __restrict__ wh1,
                                               f16* __restrict__ wh2) {
  const int i = blockIdx.x * 256 + threadIdx.x;
  const float4* src; f16* dst; int off;
  if (i < CVT_X4)               { src = (const float4*)x;  dst = xh;  off = i; }
  else if (i < CVT_X4 + CVT_W4) { src = (const float4*)w1; dst = wh1; off = i - CVT_X4; }
  else                          { src = (const float4*)w2; dst = wh2; off = i - CVT_X4 - CVT_W4; }
  const float4 v = src[off];
  union { f16 h[4]; ushort4 u; } p;
  p.h[0] = (f16)v.x; p.h[1] = (f16)v.y; p.h[2] = (f16)v.z; p.h[3] = (f16)v.w;
  *(ushort4*)(dst + (size_t)off * 4) = p.u;
}

// ---------------------------------------------------------------------------
// Shared MFMA NT-GEMM mainloop v3: 128x128 tile, 4 waves (2x2), fp16.
// 3-buffer BK=32 pipeline, 2 stages ahead, COUNTED vmcnt (T4):
//   iter i: STAGE(i+2 -> buf[(i+2)%3]); compute buf[i%3];
//           s_waitcnt vmcnt(4)  (S(i+1) proven complete, S(i+2) in flight);
//           s_barrier.
// Never drains the just-issued stage -> stage latency spans 2 compute phases.
// Race-free: buf[(i+2)%3] last read at iter i-1 (before that barrier);
// vmcnt is per-wave FIFO so vmcnt(4) with 8 outstanding == S(i+1) done.
// LDS 48KB -> 3 blocks/CU (matches qkv grid 3/CU; proj is 1/CU and gains
// most since its per-block critical path is the kernel time).
// ---------------------------------------------------------------------------
#define SUB (128 * 32)   // halves per BK=32 sub-tile buffer

__device__ __forceinline__ void gemm_mainloop(const f16* __restrict__ A,
                                              const f16* __restrict__ B,
                                              int K, int bm, int bn,
                                              f16* As, f16* Bs,
                                              f32x4 (&acc)[4][4]) {
  const int tid  = threadIdx.x;
  const int w    = tid >> 6, lane = tid & 63;
  const int wm   = w >> 1,   wn   = w & 1;
  const int ln   = lane & 15, quad = lane >> 4;
  const int sr   = lane >> 2;                                  // row in 16-row chunk
  const int sc   = (((lane & 3) ^ ((lane >> 4) & 3)) << 3);    // swizzled k-chunk (halves)
  const int ro   = ((quad ^ ((ln >> 2) & 3)) << 3);            // matching read swizzle

  const f16* Ag0 = A + (size_t)(bm + w * 16 + sr) * K + sc;
  const f16* Ag1 = A + (size_t)(bm + (w + 4) * 16 + sr) * K + sc;
  const f16* Bg0 = B + (size_t)(bn + w * 16 + sr) * K + sc;
  const f16* Bg1 = B + (size_t)(bn + (w + 4) * 16 + sr) * K + sc;
  f16* Al0 = As + (w * 16) * 32;
  f16* Al1 = As + ((w + 4) * 16) * 32;
  f16* Bl0 = Bs + (w * 16) * 32;
  f16* Bl1 = Bs + ((w + 4) * 16) * 32;

  const int NT = K >> 5;   // BK=32 tiles

  auto STAGE = [&](int t, int bi) {
    const int off = t * 32;
    const int bo  = bi * SUB;
    gl_lds16(Ag0 + off, Al0 + bo);
    gl_lds16(Ag1 + off, Al1 + bo);
    gl_lds16(Bg0 + off, Bl0 + bo);
    gl_lds16(Bg1 + off, Bl1 + bo);
  };

  // ---- prologue: stage tiles 0,1 into buffers 0,1; wait only for tile 0 ----
  STAGE(0, 0);
  STAGE(1, 1);
  asm volatile("s_waitcnt vmcnt(4)" ::: "memory");
  __builtin_amdgcn_s_barrier();
  __builtin_amdgcn_sched_barrier(0);

  int cur = 0, stg = 2;
  for (int it = 0; it < NT; ++it) {
    const bool more = (it + 2 < NT);
    if (more) STAGE(it + 2, stg);

    // ---- compute current buffer ----
    const f16* Asub = As + cur * SUB;
    const f16* Bsub = Bs + cur * SUB;
    f16x8 af[4], bf[4];
#pragma unroll
    for (int fm = 0; fm < 4; ++fm)
      af[fm] = *(const f16x8*)&Asub[(wm * 64 + fm * 16 + ln) * 32 + ro];
#pragma unroll
    for (int fn = 0; fn < 4; ++fn)
      bf[fn] = *(const f16x8*)&Bsub[(wn * 64 + fn * 16 + ln) * 32 + ro];
#pragma unroll
    for (int fm = 0; fm < 4; ++fm)
#pragma unroll
      for (int fn = 0; fn < 4; ++fn)
        acc[fm][fn] = __builtin_amdgcn_mfma_f32_16x16x32_f16(af[fm], bf[fn], acc[fm][fn], 0, 0, 0);

    // ---- counted wait: next tile's stage complete, 2-ahead stays in flight --
    if (more) asm volatile("s_waitcnt vmcnt(4)" ::: "memory");
    else      asm volatile("s_waitcnt vmcnt(0)" ::: "memory");
    __builtin_amdgcn_s_barrier();
    __builtin_amdgcn_sched_barrier(0);

    cur = (cur == 2) ? 0 : cur + 1;
    stg = (stg == 2) ? 0 : stg + 1;
  }
}

// ---------------------------------------------------------------------------
// QKV GEMM + fused epilogue:
//   q -> L2-norm -> qb[B,H,N,64]; k -> L2-norm * 0.125*log2e*s[n] -> kb;
//   v -> PV B-frag order: vfrag[bh][tk][p][lane][8], 16B/lane chunks.
// ---------------------------------------------------------------------------
__global__ __launch_bounds__(256) void gemm_qkv(const f16* __restrict__ A,
                                                const f16* __restrict__ B,
                                                const float* __restrict__ score,
                                                f16* __restrict__ qb,
                                                f16* __restrict__ kb,
                                                f16* __restrict__ vfrag) {
  __shared__ __align__(16) struct { f16 As[3 * SUB]; f16 Bs[3 * SUB]; } sm;
  f32x4 acc[4][4];
#pragma unroll
  for (int i = 0; i < 4; ++i)
#pragma unroll
    for (int j = 0; j < 4; ++j) acc[i][j] = (f32x4){0.f, 0.f, 0.f, 0.f};

  const int bm = blockIdx.y * 128, bn = blockIdx.x * 128;
  gemm_mainloop(A, B, C_DIM, bm, bn, sm.As, sm.Bs, acc);

  const int tid = threadIdx.x;
  const int w = tid >> 6, lane = tid & 63;
  const int wm = w >> 1, wn = w & 1;
  const int ln = lane & 15, quad = lane >> 4;
  const int col0 = bn + wn * 64;
  const int mode = col0 >> 10;
  const int h    = (col0 >> 6) & 15;

  if (mode <= 1) {
    f16* dst = mode ? kb : qb;
#pragma unroll
    for (int fm = 0; fm < 4; ++fm) {
#pragma unroll
      for (int r = 0; r < 4; ++r) {
        const int m = bm + wm * 64 + fm * 16 + quad * 4 + r;
        const int b = m >> 11, n = m & (N_TOK - 1);
        float ss = acc[fm][0][r] * acc[fm][0][r] + acc[fm][1][r] * acc[fm][1][r]
                 + acc[fm][2][r] * acc[fm][2][r] + acc[fm][3][r] * acc[fm][3][r];
        ss += __shfl_xor(ss, 1, 64);
        ss += __shfl_xor(ss, 2, 64);
        ss += __shfl_xor(ss, 4, 64);
        ss += __shfl_xor(ss, 8, 64);
        float sc = 1.0f / (sqrtf(ss) + 1e-8f);
        if (mode) sc *= 0.125f * LOG2E * score[n];
        f16* drow = dst + (((size_t)(b * H_DIM + h) * N_TOK + n) << 6);
#pragma unroll
        for (int fn = 0; fn < 4; ++fn)
          drow[fn * 16 + ln] = (f16)(acc[fm][fn][r] * sc);
      }
    }
  } else {
    const int m0  = bm + wm * 64;
    const int b   = m0 >> 11;
    const int tk0 = (m0 & (N_TOK - 1)) >> 4;
    f16* vb = vfrag + (((size_t)(b * H_DIM + h) * 128 + tk0) * 2) * 512 + lane * 8;
#pragma unroll
    for (int fm = 0; fm < 4; ++fm)
#pragma unroll
      for (int p = 0; p < 2; ++p) {
        f16x8 v8;
#pragma unroll
        for (int r = 0; r < 4; ++r) v8[r]     = (f16)acc[fm][2 * p][r];
#pragma unroll
        for (int r = 0; r < 4; ++r) v8[4 + r] = (f16)acc[fm][2 * p + 1][r];
        *(f16x8*)(vb + ((size_t)fm * 2 + p) * 512) = v8;
      }
  }
}

// ---------------------------------------------------------------------------
// Proj GEMM
// ---------------------------------------------------------------------------
__global__ __launch_bounds__(256) void gemm_proj(const f16* __restrict__ A,
                                                 const f16* __restrict__ B,
                                                 const float* __restrict__ bias,
                                                 float* __restrict__ out) {
  __shared__ __align__(16) struct { f16 As[3 * SUB]; f16 Bs[3 * SUB]; } sm;
  f32x4 acc[4][4];
#pragma unroll
  for (int i = 0; i < 4; ++i)
#pragma unroll
    for (int j = 0; j < 4; ++j) acc[i][j] = (f32x4){0.f, 0.f, 0.f, 0.f};

  const int bm = blockIdx.y * 128, bn = blockIdx.x * 128;
  gemm_mainloop(A, B, C_DIM, bm, bn, sm.As, sm.Bs, acc);

  const int tid = threadIdx.x;
  const int w = tid >> 6, lane = tid & 63;
  const int wm = w >> 1, wn = w & 1;
  const int ln = lane & 15, quad = lane >> 4;
  float bv[4];
#pragma unroll
  for (int fn = 0; fn < 4; ++fn) bv[fn] = bias[bn + wn * 64 + fn * 16 + ln];
#pragma unroll
  for (int fm = 0; fm < 4; ++fm)
#pragma unroll
    for (int r = 0; r < 4; ++r) {
      const int m = bm + wm * 64 + fm * 16 + quad * 4 + r;
#pragma unroll
      for (int fn = 0; fn < 4; ++fn)
        out[(size_t)m * C_DIM + bn + wn * 64 + fn * 16 + ln] = acc[fm][fn][r] + bv[fn];
    }
}

// ---------------------------------------------------------------------------
// MFMA attention v10 (unchanged): LDS-staged, double-buffered, XCD-pinned,
// K-tile XOR swizzle, setprio around MFMA clusters, raw v_exp_f32 + packed
// f16 cvt softmax. VALU-bound (46%) + MFMA (34%) ~ 80% combined issue.
// ---------------------------------------------------------------------------
__global__ __launch_bounds__(256) void attn_mfma(const f16* __restrict__ qb,
                                                 const f16* __restrict__ kb,
                                                 const f16* __restrict__ vfrag,
                                                 const float* __restrict__ score,
                                                 const int* __restrict__ usem,
                                                 f16* __restrict__ obuf) {
  __shared__ __align__(16) f16 Kl[2][64][64];
  __shared__ __align__(16) f16 Vl[2][4096];

  const int tid  = threadIdx.x;
  const int w    = tid >> 6;
  const int lane = tid & 63;
  const int ln   = lane & 15;
  const int quad = lane >> 4;
  const int bh = blockIdx.x;                 // XCD-pinned: bh%8
  const int q0 = blockIdx.y * 64;
  const int b  = bh >> 4, h = bh & 15;
  const int umask = *usem;

  // Q B-frags: 16 q rows per wave, in registers for the whole kernel
  const f16* qp = qb + ((size_t)bh * N_TOK + q0 + w * 16 + ln) * HD + quad * 8;
  const f16x8 bq0 = *(const f16x8*)(qp);
  const f16x8 bq1 = *(const f16x8*)(qp + 32);
  const float sq = score[q0 + w * 16 + ln] - 0.1f;

  f32x4 O[4], Ol;
#pragma unroll
  for (int t = 0; t < 4; ++t) O[t] = (f32x4){0.f, 0.f, 0.f, 0.f};
  Ol = (f32x4){0.f, 0.f, 0.f, 0.f};
  const f16x4 ones = (f16x4){(f16)1.f, (f16)1.f, (f16)1.f, (f16)1.f};

  const int sr  = tid >> 2;            // K stage row 0..63
  const int scc = (tid & 3) << 4;      // K stage col (halves)
  const int sw  = (sr & 7) << 3;       // write-side swizzle (halves)
  const int wc0 = scc ^ sw;            // swizzled store cols
  const int wc1 = (scc + 8) ^ sw;
  const int e3  = (ln & 7) << 3;       // read-side swizzle (halves)
  const int rc0 = (quad * 8) ^ e3;     // swizzled read cols
  const int rc1 = (32 + quad * 8) ^ e3;
  const int c0  = 2 * w, c1 = 2 * w + 1;   // V DMA chunks for this wave
  const f16* kg = kb    + (size_t)bh * N_TOK * HD;
  const f16* vg = vfrag + (size_t)bh * 128 * 1024;

  // ---- prologue: stage tile 0 into buffer 0 ----
  gl_lds16(vg + c0 * 512 + lane * 8, &Vl[0][c0 * 512]);
  gl_lds16(vg + c1 * 512 + lane * 8, &Vl[0][c1 * 512]);
  {
    const float4 k0r = *(const float4*)(kg + (size_t)sr * HD + scc);
    const float4 k1r = *(const float4*)(kg + (size_t)sr * HD + scc + 8);
    *(float4*)&Kl[0][sr][wc0] = k0r;
    *(float4*)&Kl[0][sr][wc1] = k1r;
  }
  __syncthreads();

  auto body = [&](int k0, int cur, int nxt) {
    // ---- prefetch tile t+1: V via DMA into nxt, K into registers ----
    const int kn = (k0 + 64 < N_TOK) ? k0 + 64 : 0;
    const f16* vt = vg + (size_t)(kn >> 4) * 1024;
    gl_lds16(vt + c0 * 512 + lane * 8, &Vl[nxt][c0 * 512]);
    gl_lds16(vt + c1 * 512 + lane * 8, &Vl[nxt][c1 * 512]);
    const float4 kn0 = *(const float4*)(kg + (size_t)(kn + sr) * HD + scc);
    const float4 kn1 = *(const float4*)(kg + (size_t)(kn + sr) * HD + scc + 8);

    // ---- S^T = K.Q^T from Kl[cur] (swizzled reads) ----
    f16x4 af[4];
    f32x4 c[4];
    __builtin_amdgcn_s_setprio(1);
#pragma unroll
    for (int t = 0; t < 4; ++t) {
      const f16x8 ka0 = *(const f16x8*)&Kl[cur][t * 16 + ln][rc0];
      const f16x8 ka1 = *(const f16x8*)&Kl[cur][t * 16 + ln][rc1];
      f32x4 cc = (f32x4){0.f, 0.f, 0.f, 0.f};
      cc = __builtin_amdgcn_mfma_f32_16x16x32_f16(ka0, bq0, cc, 0, 0, 0);
      cc = __builtin_amdgcn_mfma_f32_16x16x32_f16(ka1, bq1, cc, 0, 0, 0);
      c[t] = cc;
    }
    __builtin_amdgcn_s_setprio(0);

    // ---- softmax in-register (log2 domain; masked -> exp2(0)=1) ----
#pragma unroll
    for (int t = 0; t < 4; ++t) {
      const float4 sk = *(const float4*)&score[k0 + t * 16 + quad * 4];
      const float skr[4] = {sk.x, sk.y, sk.z, sk.w};
      float e[4];
#pragma unroll
      for (int r = 0; r < 4; ++r) {
        float x = c[t][r];
        if (umask && !(skr[r] > sq)) x = 0.f;
        e[r] = __builtin_amdgcn_exp2f(x);
      }
      union { fp16x2_b p[2]; f16x4 v; } u;
      u.p[0] = __builtin_amdgcn_cvt_pkrtz(e[0], e[1]);
      u.p[1] = __builtin_amdgcn_cvt_pkrtz(e[2], e[3]);
      af[t] = u.v;
    }

    // ---- O += P V from Vl[cur]; l accumulated via ones-frag MFMA ----
    __builtin_amdgcn_s_setprio(1);
#pragma unroll
    for (int t = 0; t < 4; ++t) {
      Ol = __builtin_amdgcn_mfma_f32_16x16x16f16(af[t], ones, Ol, 0, 0, 0);
#pragma unroll
      for (int p = 0; p < 2; ++p) {
        const f16x8 vv = *(const f16x8*)&Vl[cur][(t * 2 + p) * 512 + lane * 8];
        const f16x4 vlo = __builtin_shufflevector(vv, vv, 0, 1, 2, 3);
        const f16x4 vhi = __builtin_shufflevector(vv, vv, 4, 5, 6, 7);
        O[2 * p]     = __builtin_amdgcn_mfma_f32_16x16x16f16(af[t], vlo, O[2 * p], 0, 0, 0);
        O[2 * p + 1] = __builtin_amdgcn_mfma_f32_16x16x16f16(af[t], vhi, O[2 * p + 1], 0, 0, 0);
      }
    }
    __builtin_amdgcn_s_setprio(0);

    // ---- stage prefetched K into Kl[nxt] (swizzled); barrier flips buffers --
    *(float4*)&Kl[nxt][sr][wc0] = kn0;
    *(float4*)&Kl[nxt][sr][wc1] = kn1;
    __syncthreads();
  };

  for (int k0 = 0; k0 < N_TOK; k0 += 128) {
    body(k0, 0, 1);
    body(k0 + 64, 1, 0);
  }

  // ---- epilogue: l for q=quad*4+r sits in Ol[r] on every lane ----
#pragma unroll
  for (int r = 0; r < 4; ++r) {
    const float inv = 1.0f / Ol[r];
    const size_t row = (size_t)(b * N_TOK + q0 + w * 16 + quad * 4 + r);
#pragma unroll
    for (int t2 = 0; t2 < 4; ++t2)
      obuf[row * C_DIM + h * HD + t2 * 16 + ln] = (f16)(O[t2][r] * inv);
  }
}

// ---------------------------------------------------------------------------
extern "C" void kernel_launch(void* const* d_in, const int* in_sizes, int n_in,
                              void* d_out, int out_size, void* d_ws, size_t ws_size,
                              hipStream_t stream) {
  const float* x      = (const float*)d_in[0];
  const float* score  = (const float*)d_in[1];
  const float* qkv_w  = (const float*)d_in[2];
  const float* proj_w = (const float*)d_in[3];
  const float* proj_b = (const float*)d_in[4];
  const int*   usem   = (const int*)d_in[5];
  float* out = (float*)d_out;

  f16* xh    = (f16*)d_ws;
  f16* wh    = xh  + (size_t)M_TOK * C_DIM;
  f16* pwh   = wh  + (size_t)3 * C_DIM * C_DIM;
  f16* qb    = pwh + (size_t)C_DIM * C_DIM;
  f16* kb    = qb  + (size_t)M_TOK * C_DIM;
  f16* vfrag = kb  + (size_t)M_TOK * C_DIM;
  f16* obuf  = vfrag + (size_t)M_TOK * C_DIM;

  cvt_all<<<(CVT_X4 + CVT_W4 + CVT_P4) / 256, 256, 0, stream>>>(x, qkv_w, proj_w, xh, wh, pwh);
  {
    dim3 grid(3 * C_DIM / 128, M_TOK / 128);
    gemm_qkv<<<grid, 256, 0, stream>>>(xh, wh, score, qb, kb, vfrag);
  }
  {
    dim3 grid(2 * H_DIM, N_TOK / 64);   // bh fastest -> XCD-pinned K/V
    attn_mfma<<<grid, 256, 0, stream>>>(qb, kb, vfrag, score, usem, obuf);
  }
  {
    dim3 grid(C_DIM / 128, M_TOK / 128);
    gemm_proj<<<grid, 256, 0, stream>>>(obuf, pwh, proj_b, out);
  }
}

// Round 7
// 193.410 us; speedup vs baseline: 1.0576x; 1.0576x over previous
//
#include <hip/hip_runtime.h>
#include <cmath>

#define C_DIM   1024
#define H_DIM   16
#define HD      64
#define N_TOK   2048
#define M_TOK   4096
#define LOG2E   1.44269504088896340736f

typedef _Float16 f16;
typedef __attribute__((ext_vector_type(8))) _Float16 f16x8;
typedef __attribute__((ext_vector_type(4))) _Float16 f16x4;
typedef __attribute__((ext_vector_type(2))) __fp16   fp16x2_b;  // builtin ret type
typedef __attribute__((ext_vector_type(4))) float    f32x4;

// async global->LDS, 16B per lane; LDS dest = wave-uniform base + lane*16
__device__ __forceinline__ void gl_lds16(const void* g, void* l) {
  __builtin_amdgcn_global_load_lds((const __attribute__((address_space(1))) void*)g,
                                   (__attribute__((address_space(3))) void*)l, 16, 0, 0);
}

// ---------------------------------------------------------------------------
// fp32 -> fp16 convert: x (4.19M), qkv_w (3.15M), proj_w (1.05M), float4/thread
// ---------------------------------------------------------------------------
#define CVT_X4 1048576
#define CVT_W4 786432
#define CVT_P4 262144
__global__ __launch_bounds__(256) void cvt_all(const float* __restrict__ x,
                                               const float* __restrict__ w1,
                                               const float* __restrict__ w2,
                                               f16* __restrict__ xh,
                                               f16* __restrict__ wh1,
                                               f16* __restrict__ wh2) {
  const int i = blockIdx.x * 256 + threadIdx.x;
  const float4* src; f16* dst; int off;
  if (i < CVT_X4)               { src = (const float4*)x;  dst = xh;  off = i; }
  else if (i < CVT_X4 + CVT_W4) { src = (const float4*)w1; dst = wh1; off = i - CVT_X4; }
  else                          { src = (const float4*)w2; dst = wh2; off = i - CVT_X4 - CVT_W4; }
  const float4 v = src[off];
  union { f16 h[4]; ushort4 u; } p;
  p.h[0] = (f16)v.x; p.h[1] = (f16)v.y; p.h[2] = (f16)v.z; p.h[3] = (f16)v.w;
  *(ushort4*)(dst + (size_t)off * 4) = p.u;
}

// ---------------------------------------------------------------------------
// Shared MFMA NT-GEMM mainloop (R5 version, best measured): 128x128 tile,
// 4 waves (2x2), fp16. 2-PHASE double-buffered BK=32: STAGE(next -> buf^1)
// issued BEFORE compute(cur), one __syncthreads per iter (implicit vmcnt(0)
// completes the staged DMA for the next iter). 32 KB LDS.
// R6 lesson: 3-buffer counted-vmcnt was neutral-to-worse at 128^2 tile —
// stage latency already hidden by multi-block TLP. Reverted.
// ---------------------------------------------------------------------------
#define SUB (128 * 32)   // halves per BK=32 sub-tile buffer

__device__ __forceinline__ void gemm_mainloop(const f16* __restrict__ A,
                                              const f16* __restrict__ B,
                                              int K, int bm, int bn,
                                              f16* As, f16* Bs,
                                              f32x4 (&acc)[4][4]) {
  const int tid  = threadIdx.x;
  const int w    = tid >> 6, lane = tid & 63;
  const int wm   = w >> 1,   wn   = w & 1;
  const int ln   = lane & 15, quad = lane >> 4;
  const int sr   = lane >> 2;                                  // row in 16-row chunk
  const int sc   = (((lane & 3) ^ ((lane >> 4) & 3)) << 3);    // swizzled k-chunk (halves)
  const int ro   = ((quad ^ ((ln >> 2) & 3)) << 3);            // matching read swizzle

  const f16* Ag0 = A + (size_t)(bm + w * 16 + sr) * K + sc;
  const f16* Ag1 = A + (size_t)(bm + (w + 4) * 16 + sr) * K + sc;
  const f16* Bg0 = B + (size_t)(bn + w * 16 + sr) * K + sc;
  const f16* Bg1 = B + (size_t)(bn + (w + 4) * 16 + sr) * K + sc;
  f16* Al0 = As + (w * 16) * 32;
  f16* Al1 = As + ((w + 4) * 16) * 32;
  f16* Bl0 = Bs + (w * 16) * 32;
  f16* Bl1 = Bs + ((w + 4) * 16) * 32;

  // ---- prologue: stage k=0 into buffer 0 ----
  gl_lds16(Ag0, Al0);
  gl_lds16(Ag1, Al1);
  gl_lds16(Bg0, Bl0);
  gl_lds16(Bg1, Bl1);
  __syncthreads();

  int cur = 0;
  for (int k0 = 0; k0 < K; k0 += 32) {
    const int nxt = cur ^ 1;
    // ---- issue next-tile DMA first (overlaps with compute below) ----
    if (k0 + 32 < K) {
      gl_lds16(Ag0 + k0 + 32, Al0 + nxt * SUB);
      gl_lds16(Ag1 + k0 + 32, Al1 + nxt * SUB);
      gl_lds16(Bg0 + k0 + 32, Bl0 + nxt * SUB);
      gl_lds16(Bg1 + k0 + 32, Bl1 + nxt * SUB);
    }
    // ---- compute current buffer ----
    const f16* Asub = As + cur * SUB;
    const f16* Bsub = Bs + cur * SUB;
    f16x8 af[4], bf[4];
#pragma unroll
    for (int fm = 0; fm < 4; ++fm)
      af[fm] = *(const f16x8*)&Asub[(wm * 64 + fm * 16 + ln) * 32 + ro];
#pragma unroll
    for (int fn = 0; fn < 4; ++fn)
      bf[fn] = *(const f16x8*)&Bsub[(wn * 64 + fn * 16 + ln) * 32 + ro];
#pragma unroll
    for (int fm = 0; fm < 4; ++fm)
#pragma unroll
      for (int fn = 0; fn < 4; ++fn)
        acc[fm][fn] = __builtin_amdgcn_mfma_f32_16x16x32_f16(af[fm], bf[fn], acc[fm][fn], 0, 0, 0);
    // one barrier per iter; implicit vmcnt(0) completes the staged DMA
    __syncthreads();
    cur = nxt;
  }
}

// ---------------------------------------------------------------------------
// QKV GEMM + fused epilogue:
//   q -> L2-norm -> qb[B,H,N,64]; k -> L2-norm * 0.125*log2e*s[n] -> kb;
//   v -> PV B-frag order: vfrag[bh][tk][p][lane][8], 16B/lane chunks.
// ---------------------------------------------------------------------------
__global__ __launch_bounds__(256) void gemm_qkv(const f16* __restrict__ A,
                                                const f16* __restrict__ B,
                                                const float* __restrict__ score,
                                                f16* __restrict__ qb,
                                                f16* __restrict__ kb,
                                                f16* __restrict__ vfrag) {
  __shared__ __align__(16) struct { f16 As[2 * SUB]; f16 Bs[2 * SUB]; } sm;
  f32x4 acc[4][4];
#pragma unroll
  for (int i = 0; i < 4; ++i)
#pragma unroll
    for (int j = 0; j < 4; ++j) acc[i][j] = (f32x4){0.f, 0.f, 0.f, 0.f};

  const int bm = blockIdx.y * 128, bn = blockIdx.x * 128;
  gemm_mainloop(A, B, C_DIM, bm, bn, sm.As, sm.Bs, acc);

  const int tid = threadIdx.x;
  const int w = tid >> 6, lane = tid & 63;
  const int wm = w >> 1, wn = w & 1;
  const int ln = lane & 15, quad = lane >> 4;
  const int col0 = bn + wn * 64;
  const int mode = col0 >> 10;
  const int h    = (col0 >> 6) & 15;

  if (mode <= 1) {
    f16* dst = mode ? kb : qb;
#pragma unroll
    for (int fm = 0; fm < 4; ++fm) {
#pragma unroll
      for (int r = 0; r < 4; ++r) {
        const int m = bm + wm * 64 + fm * 16 + quad * 4 + r;
        const int b = m >> 11, n = m & (N_TOK - 1);
        float ss = acc[fm][0][r] * acc[fm][0][r] + acc[fm][1][r] * acc[fm][1][r]
                 + acc[fm][2][r] * acc[fm][2][r] + acc[fm][3][r] * acc[fm][3][r];
        ss += __shfl_xor(ss, 1, 64);
        ss += __shfl_xor(ss, 2, 64);
        ss += __shfl_xor(ss, 4, 64);
        ss += __shfl_xor(ss, 8, 64);
        float sc = 1.0f / (sqrtf(ss) + 1e-8f);
        if (mode) sc *= 0.125f * LOG2E * score[n];
        f16* drow = dst + (((size_t)(b * H_DIM + h) * N_TOK + n) << 6);
#pragma unroll
        for (int fn = 0; fn < 4; ++fn)
          drow[fn * 16 + ln] = (f16)(acc[fm][fn][r] * sc);
      }
    }
  } else {
    const int m0  = bm + wm * 64;
    const int b   = m0 >> 11;
    const int tk0 = (m0 & (N_TOK - 1)) >> 4;
    f16* vb = vfrag + (((size_t)(b * H_DIM + h) * 128 + tk0) * 2) * 512 + lane * 8;
#pragma unroll
    for (int fm = 0; fm < 4; ++fm)
#pragma unroll
      for (int p = 0; p < 2; ++p) {
        f16x8 v8;
#pragma unroll
        for (int r = 0; r < 4; ++r) v8[r]     = (f16)acc[fm][2 * p][r];
#pragma unroll
        for (int r = 0; r < 4; ++r) v8[4 + r] = (f16)acc[fm][2 * p + 1][r];
        *(f16x8*)(vb + ((size_t)fm * 2 + p) * 512) = v8;
      }
  }
}

// ---------------------------------------------------------------------------
// Proj GEMM
// ---------------------------------------------------------------------------
__global__ __launch_bounds__(256) void gemm_proj(const f16* __restrict__ A,
                                                 const f16* __restrict__ B,
                                                 const float* __restrict__ bias,
                                                 float* __restrict__ out) {
  __shared__ __align__(16) struct { f16 As[2 * SUB]; f16 Bs[2 * SUB]; } sm;
  f32x4 acc[4][4];
#pragma unroll
  for (int i = 0; i < 4; ++i)
#pragma unroll
    for (int j = 0; j < 4; ++j) acc[i][j] = (f32x4){0.f, 0.f, 0.f, 0.f};

  const int bm = blockIdx.y * 128, bn = blockIdx.x * 128;
  gemm_mainloop(A, B, C_DIM, bm, bn, sm.As, sm.Bs, acc);

  const int tid = threadIdx.x;
  const int w = tid >> 6, lane = tid & 63;
  const int wm = w >> 1, wn = w & 1;
  const int ln = lane & 15, quad = lane >> 4;
  float bv[4];
#pragma unroll
  for (int fn = 0; fn < 4; ++fn) bv[fn] = bias[bn + wn * 64 + fn * 16 + ln];
#pragma unroll
  for (int fm = 0; fm < 4; ++fm)
#pragma unroll
    for (int r = 0; r < 4; ++r) {
      const int m = bm + wm * 64 + fm * 16 + quad * 4 + r;
#pragma unroll
      for (int fn = 0; fn < 4; ++fn)
        out[(size_t)m * C_DIM + bn + wn * 64 + fn * 16 + ln] = acc[fm][fn][r] + bv[fn];
    }
}

// ---------------------------------------------------------------------------
// MFMA attention v11: 8-wave blocks, 128 q-rows/block (2x work per staged
// K/V tile). Each wave keeps 16 q-rows; staging per unit work HALVES:
// V: 1 gl_lds16 per wave (8 chunks / 8 waves); K: one float4 per thread
// (8KB / 512 threads). Barriers per work halve; per-block L2 K/V re-read
// halves (512->256 MB); occupancy 11 -> 16 waves/CU (512 blocks = 2/CU).
// MFMA/softmax structure, XOR swizzle, setprio, exp2/cvt_pkrtz unchanged.
// ---------------------------------------------------------------------------
__global__ __launch_bounds__(512) void attn_mfma(const f16* __restrict__ qb,
                                                 const f16* __restrict__ kb,
                                                 const f16* __restrict__ vfrag,
                                                 const float* __restrict__ score,
                                                 const int* __restrict__ usem,
                                                 f16* __restrict__ obuf) {
  __shared__ __align__(16) f16 Kl[2][64][64];
  __shared__ __align__(16) f16 Vl[2][4096];

  const int tid  = threadIdx.x;
  const int w    = tid >> 6;           // 0..7
  const int lane = tid & 63;
  const int ln   = lane & 15;
  const int quad = lane >> 4;
  const int bh = blockIdx.x;                 // XCD-pinned: bh%8
  const int q0 = blockIdx.y * 128;
  const int b  = bh >> 4, h = bh & 15;
  const int umask = *usem;

  // Q B-frags: 16 q rows per wave (8 waves = 128 rows), in registers
  const f16* qp = qb + ((size_t)bh * N_TOK + q0 + w * 16 + ln) * HD + quad * 8;
  const f16x8 bq0 = *(const f16x8*)(qp);
  const f16x8 bq1 = *(const f16x8*)(qp + 32);
  const float sq = score[q0 + w * 16 + ln] - 0.1f;

  f32x4 O[4], Ol;
#pragma unroll
  for (int t = 0; t < 4; ++t) O[t] = (f32x4){0.f, 0.f, 0.f, 0.f};
  Ol = (f32x4){0.f, 0.f, 0.f, 0.f};
  const f16x4 ones = (f16x4){(f16)1.f, (f16)1.f, (f16)1.f, (f16)1.f};

  const int sr  = tid >> 3;            // K stage row 0..63
  const int scc = (tid & 7) << 3;      // K stage col (halves, 16B per thread)
  const int sw  = (sr & 7) << 3;       // write-side swizzle (halves)
  const int wc0 = scc ^ sw;            // swizzled store col
  const int e3  = (ln & 7) << 3;       // read-side swizzle (halves)
  const int rc0 = (quad * 8) ^ e3;     // swizzled read cols
  const int rc1 = (32 + quad * 8) ^ e3;
  const int c0  = w;                   // V DMA chunk for this wave (1 of 8)
  const f16* kg = kb    + (size_t)bh * N_TOK * HD;
  const f16* vg = vfrag + (size_t)bh * 128 * 1024;

  // ---- prologue: stage tile 0 into buffer 0 ----
  gl_lds16(vg + c0 * 512 + lane * 8, &Vl[0][c0 * 512]);
  {
    const float4 k0r = *(const float4*)(kg + (size_t)sr * HD + scc);
    *(float4*)&Kl[0][sr][wc0] = k0r;
  }
  __syncthreads();

  auto body = [&](int k0, int cur, int nxt) {
    // ---- prefetch tile t+1: V via DMA into nxt, K into registers ----
    const int kn = (k0 + 64 < N_TOK) ? k0 + 64 : 0;
    const f16* vt = vg + (size_t)(kn >> 4) * 1024;
    gl_lds16(vt + c0 * 512 + lane * 8, &Vl[nxt][c0 * 512]);
    const float4 kn0 = *(const float4*)(kg + (size_t)(kn + sr) * HD + scc);

    // ---- S^T = K.Q^T from Kl[cur] (swizzled reads) ----
    f16x4 af[4];
    f32x4 c[4];
    __builtin_amdgcn_s_setprio(1);
#pragma unroll
    for (int t = 0; t < 4; ++t) {
      const f16x8 ka0 = *(const f16x8*)&Kl[cur][t * 16 + ln][rc0];
      const f16x8 ka1 = *(const f16x8*)&Kl[cur][t * 16 + ln][rc1];
      f32x4 cc = (f32x4){0.f, 0.f, 0.f, 0.f};
      cc = __builtin_amdgcn_mfma_f32_16x16x32_f16(ka0, bq0, cc, 0, 0, 0);
      cc = __builtin_amdgcn_mfma_f32_16x16x32_f16(ka1, bq1, cc, 0, 0, 0);
      c[t] = cc;
    }
    __builtin_amdgcn_s_setprio(0);

    // ---- softmax in-register (log2 domain; masked -> exp2(0)=1) ----
#pragma unroll
    for (int t = 0; t < 4; ++t) {
      const float4 sk = *(const float4*)&score[k0 + t * 16 + quad * 4];
      const float skr[4] = {sk.x, sk.y, sk.z, sk.w};
      float e[4];
#pragma unroll
      for (int r = 0; r < 4; ++r) {
        float x = c[t][r];
        if (umask && !(skr[r] > sq)) x = 0.f;
        e[r] = __builtin_amdgcn_exp2f(x);
      }
      union { fp16x2_b p[2]; f16x4 v; } u;
      u.p[0] = __builtin_amdgcn_cvt_pkrtz(e[0], e[1]);
      u.p[1] = __builtin_amdgcn_cvt_pkrtz(e[2], e[3]);
      af[t] = u.v;
    }

    // ---- O += P V from Vl[cur]; l accumulated via ones-frag MFMA ----
    __builtin_amdgcn_s_setprio(1);
#pragma unroll
    for (int t = 0; t < 4; ++t) {
      Ol = __builtin_amdgcn_mfma_f32_16x16x16f16(af[t], ones, Ol, 0, 0, 0);
#pragma unroll
      for (int p = 0; p < 2; ++p) {
        const f16x8 vv = *(const f16x8*)&Vl[cur][(t * 2 + p) * 512 + lane * 8];
        const f16x4 vlo = __builtin_shufflevector(vv, vv, 0, 1, 2, 3);
        const f16x4 vhi = __builtin_shufflevector(vv, vv, 4, 5, 6, 7);
        O[2 * p]     = __builtin_amdgcn_mfma_f32_16x16x16f16(af[t], vlo, O[2 * p], 0, 0, 0);
        O[2 * p + 1] = __builtin_amdgcn_mfma_f32_16x16x16f16(af[t], vhi, O[2 * p + 1], 0, 0, 0);
      }
    }
    __builtin_amdgcn_s_setprio(0);

    // ---- stage prefetched K into Kl[nxt] (swizzled); barrier flips buffers --
    *(float4*)&Kl[nxt][sr][wc0] = kn0;
    __syncthreads();
  };

  for (int k0 = 0; k0 < N_TOK; k0 += 128) {
    body(k0, 0, 1);
    body(k0 + 64, 1, 0);
  }

  // ---- epilogue: l for q=quad*4+r sits in Ol[r] on every lane ----
#pragma unroll
  for (int r = 0; r < 4; ++r) {
    const float inv = 1.0f / Ol[r];
    const size_t row = (size_t)(b * N_TOK + q0 + w * 16 + quad * 4 + r);
#pragma unroll
    for (int t2 = 0; t2 < 4; ++t2)
      obuf[row * C_DIM + h * HD + t2 * 16 + ln] = (f16)(O[t2][r] * inv);
  }
}

// ---------------------------------------------------------------------------
extern "C" void kernel_launch(void* const* d_in, const int* in_sizes, int n_in,
                              void* d_out, int out_size, void* d_ws, size_t ws_size,
                              hipStream_t stream) {
  const float* x      = (const float*)d_in[0];
  const float* score  = (const float*)d_in[1];
  const float* qkv_w  = (const float*)d_in[2];
  const float* proj_w = (const float*)d_in[3];
  const float* proj_b = (const float*)d_in[4];
  const int*   usem   = (const int*)d_in[5];
  float* out = (float*)d_out;

  f16* xh    = (f16*)d_ws;
  f16* wh    = xh  + (size_t)M_TOK * C_DIM;
  f16* pwh   = wh  + (size_t)3 * C_DIM * C_DIM;
  f16* qb    = pwh + (size_t)C_DIM * C_DIM;
  f16* kb    = qb  + (size_t)M_TOK * C_DIM;
  f16* vfrag = kb  + (size_t)M_TOK * C_DIM;
  f16* obuf  = vfrag + (size_t)M_TOK * C_DIM;

  cvt_all<<<(CVT_X4 + CVT_W4 + CVT_P4) / 256, 256, 0, stream>>>(x, qkv_w, proj_w, xh, wh, pwh);
  {
    dim3 grid(3 * C_DIM / 128, M_TOK / 128);
    gemm_qkv<<<grid, 256, 0, stream>>>(xh, wh, score, qb, kb, vfrag);
  }
  {
    dim3 grid(2 * H_DIM, N_TOK / 128);   // bh fastest -> XCD-pinned K/V
    attn_mfma<<<grid, 512, 0, stream>>>(qb, kb, vfrag, score, usem, obuf);
  }
  {
    dim3 grid(C_DIM / 128, M_TOK / 128);
    gemm_proj<<<grid, 256, 0, stream>>>(obuf, pwh, proj_b, out);
  }
}